// Round 2
// baseline (11974.663 us; speedup 1.0000x reference)
//
#include <hip/hip_runtime.h>
#include <math.h>

#define N_PTS 16384
#define KNN 20

// ---------------- squared norms ----------------
__global__ void sq3_kernel(const float* __restrict__ x, float* __restrict__ sq) {
  int i = blockIdx.x * blockDim.x + threadIdx.x;
  {
    #pragma clang fp contract(off)
    float a = x[i*3+0], b = x[i*3+1], c = x[i*3+2];
    sq[i] = a*a + b*b + c*c;
  }
}

__global__ void sq64_kernel(const float* __restrict__ h, float* __restrict__ sq) {
  int i = blockIdx.x * blockDim.x + threadIdx.x;
  const float4* r = (const float4*)(h + (long)i*64);
  {
    #pragma clang fp contract(off)
    float ax=0.f, ay=0.f, az=0.f, aw=0.f;
    for (int t=0; t<16; t++) {
      float4 v = r[t];
      ax += v.x*v.x; ay += v.y*v.y; az += v.z*v.z; aw += v.w*v.w;
    }
    sq[i] = (ax+ay)+(az+aw);
  }
}

// ---------------- knn, D=3 ----------------
// one wave per query; per-lane sorted top-20 lists in LDS; lex tie-break on index
__global__ __launch_bounds__(256) void knn3_kernel(const float* __restrict__ x,
                                                   const float* __restrict__ sq,
                                                   int* __restrict__ out_idx) {
  __shared__ float s_bd[KNN*256];
  __shared__ int   s_bi[KNN*256];
  int tid = threadIdx.x;
  int lane = tid & 63;
  int qi = blockIdx.x*4 + (tid >> 6);

  float qx = x[qi*3+0], qy = x[qi*3+1], qz = x[qi*3+2];
  float sqi = sq[qi];
  for (int p=0; p<KNN; p++) { s_bd[p*256+tid] = INFINITY; s_bi[p*256+tid] = 0x7fffffff; }

  for (int j = lane; j < N_PTS; j += 64) {
    float d;
    {
      #pragma clang fp contract(off)
      float fx = x[j*3+0], fy = x[j*3+1], fz = x[j*3+2];
      float dot = qx*fx + qy*fy + qz*fz;
      d = (sqi + sq[j]) - 2.0f*dot;
    }
    float worst = s_bd[(KNN-1)*256+tid];
    if (d < worst || (d == worst && j < s_bi[(KNN-1)*256+tid])) {
      int p = KNN-1;
      while (p > 0) {
        float pd = s_bd[(p-1)*256+tid];
        int   pi = s_bi[(p-1)*256+tid];
        if (pd > d || (pd == d && pi > j)) { s_bd[p*256+tid]=pd; s_bi[p*256+tid]=pi; p--; }
        else break;
      }
      s_bd[p*256+tid] = d; s_bi[p*256+tid] = j;
    }
  }

  // wave merge: 20 rounds of lex argmin over the 64 sorted lists
  int pos = 0;
  float cd = s_bd[0*256+tid]; int ci = s_bi[0*256+tid];
  for (int r=0; r<KNN; r++) {
    float d = cd; int ii = ci; int src = lane;
    for (int off=32; off; off>>=1) {
      float d2 = __shfl_xor(d, off, 64);
      int   i2 = __shfl_xor(ii, off, 64);
      int   s2 = __shfl_xor(src, off, 64);
      if (d2 < d || (d2 == d && i2 < ii)) { d=d2; ii=i2; src=s2; }
    }
    if (lane == src) {
      pos++;
      if (pos < KNN) { cd = s_bd[pos*256+tid]; ci = s_bi[pos*256+tid]; }
      else           { cd = INFINITY; ci = 0x7fffffff; }
    }
    if (lane == 0) out_idx[qi*KNN + r] = ii;
  }
}

// ---------------- knn, D=64 ----------------
__global__ __launch_bounds__(256) void knn64_kernel(const float* __restrict__ h,
                                                    const float* __restrict__ sq,
                                                    int* __restrict__ out_idx) {
  __shared__ float s_bd[KNN*256];
  __shared__ int   s_bi[KNN*256];
  __shared__ float qbuf[4][64];
  int tid = threadIdx.x;
  int lane = tid & 63;
  int w = tid >> 6;
  int qi = blockIdx.x*4 + w;

  qbuf[w][lane] = h[(long)qi*64 + lane];
  float sqi = sq[qi];
  for (int p=0; p<KNN; p++) { s_bd[p*256+tid] = INFINITY; s_bi[p*256+tid] = 0x7fffffff; }
  __syncthreads();

  const float4* q4 = (const float4*)qbuf[w];
  for (int j = lane; j < N_PTS; j += 64) {
    float d;
    {
      #pragma clang fp contract(off)
      const float4* r4 = (const float4*)(h + (long)j*64);
      float ax=0.f, ay=0.f, az=0.f, aw=0.f;
      for (int t=0; t<16; t++) {
        float4 a = q4[t], b = r4[t];
        ax += a.x*b.x; ay += a.y*b.y; az += a.z*b.z; aw += a.w*b.w;
      }
      float dot = (ax+ay)+(az+aw);
      d = (sqi + sq[j]) - 2.0f*dot;
    }
    float worst = s_bd[(KNN-1)*256+tid];
    if (d < worst || (d == worst && j < s_bi[(KNN-1)*256+tid])) {
      int p = KNN-1;
      while (p > 0) {
        float pd = s_bd[(p-1)*256+tid];
        int   pi = s_bi[(p-1)*256+tid];
        if (pd > d || (pd == d && pi > j)) { s_bd[p*256+tid]=pd; s_bi[p*256+tid]=pi; p--; }
        else break;
      }
      s_bd[p*256+tid] = d; s_bi[p*256+tid] = j;
    }
  }

  int pos = 0;
  float cd = s_bd[0*256+tid]; int ci = s_bi[0*256+tid];
  for (int r=0; r<KNN; r++) {
    float d = cd; int ii = ci; int src = lane;
    for (int off=32; off; off>>=1) {
      float d2 = __shfl_xor(d, off, 64);
      int   i2 = __shfl_xor(ii, off, 64);
      int   s2 = __shfl_xor(src, off, 64);
      if (d2 < d || (d2 == d && i2 < ii)) { d=d2; ii=i2; src=s2; }
    }
    if (lane == src) {
      pos++;
      if (pos < KNN) { cd = s_bd[pos*256+tid]; ci = s_bi[pos*256+tid]; }
      else           { cd = INFINITY; ci = 0x7fffffff; }
    }
    if (lane == 0) out_idx[qi*KNN + r] = ii;
  }
}

// ---------------- edge_conv1 precompute: C1 = x@(W1t-W1b)+b1, G1 = x@W1b ----------------
__global__ void cg1_kernel(const float* __restrict__ x, const float* __restrict__ W1,
                           const float* __restrict__ b1,
                           float* __restrict__ C1, float* __restrict__ G1) {
  int gid = blockIdx.x*256 + threadIdx.x;   // 16384*64
  int i = gid >> 6, c = gid & 63;
  float x0 = x[i*3+0], x1 = x[i*3+1], x2 = x[i*3+2];
  float wt0 = W1[0*64+c], wt1 = W1[1*64+c], wt2 = W1[2*64+c];
  float wb0 = W1[3*64+c], wb1 = W1[4*64+c], wb2 = W1[5*64+c];
  C1[gid] = x0*(wt0-wb0) + x1*(wt1-wb1) + x2*(wt2-wb2) + b1[c];
  G1[gid] = x0*wb0 + x1*wb1 + x2*wb2;
}

// ---------------- gather + max + relu ----------------
template<int C>
__global__ void maxrelu_kernel(const float* __restrict__ Ci, const float* __restrict__ G,
                               const int* __restrict__ idx, float* __restrict__ out) {
  int gid = blockIdx.x*256 + threadIdx.x;
  int i = gid / C, c = gid % C;
  float base = Ci[gid];
  float m = -INFINITY;
  for (int j=0; j<KNN; j++) {
    int jj = idx[i*KNN + j];
    m = fmaxf(m, base + G[(long)jj*C + c]);
  }
  out[gid] = fmaxf(m, 0.0f);
}

// ---------------- W2 diff ----------------
__global__ void wd2_kernel(const float* __restrict__ W2, float* __restrict__ Wd) {
  int gid = blockIdx.x*256 + threadIdx.x;   // 64*128
  int d = gid >> 7, c = gid & 127;
  Wd[gid] = W2[d*128+c] - W2[(d+64)*128+c];
}

// ---------------- edge_conv2 precompute: C2 = h1@Wd2+b2, G2 = h1@W2_bot ----------------
__global__ void cg2_kernel(const float* __restrict__ h1, const float* __restrict__ W2,
                           const float* __restrict__ Wd, const float* __restrict__ b2,
                           float* __restrict__ C2, float* __restrict__ G2) {
  int gid = blockIdx.x*256 + threadIdx.x;   // 16384*128
  int i = gid >> 7, c = gid & 127;
  float a = 0.f, g = 0.f;
  for (int d=0; d<64; d++) {
    float hv = h1[i*64 + d];
    a += hv * Wd[d*128 + c];
    g += hv * W2[(d+64)*128 + c];
  }
  C2[gid] = a + b2[c];
  G2[gid] = g;
}

// ---------------- fc1 (relu) ----------------
__global__ void fc1_kernel(const float* __restrict__ h2, const float* __restrict__ w,
                           const float* __restrict__ b, float* __restrict__ out) {
  int gid = blockIdx.x*256 + threadIdx.x;   // 16384*128
  int i = gid >> 7, c = gid & 127;
  float a = 0.f;
  for (int d=0; d<128; d++) a += h2[i*128+d] * w[d*128+c];
  out[gid] = fmaxf(a + b[c], 0.0f);
}

// ---------------- fc2 ----------------
__global__ void fc2_kernel(const float* __restrict__ f1, const float* __restrict__ w,
                           const float* __restrict__ b, float* __restrict__ out) {
  int gid = blockIdx.x*256 + threadIdx.x;   // 16384*40
  int i = gid / 40, c = gid - i*40;
  float a = 0.f;
  for (int d=0; d<128; d++) a += f1[i*128+d] * w[d*40+c];
  out[gid] = a + b[c];
}

extern "C" void kernel_launch(void* const* d_in, const int* in_sizes, int n_in,
                              void* d_out, int out_size, void* d_ws, size_t ws_size,
                              hipStream_t stream) {
  (void)in_sizes; (void)n_in; (void)out_size; (void)ws_size;
  const float* x     = (const float*)d_in[0];
  const float* W1    = (const float*)d_in[1];
  const float* b1    = (const float*)d_in[2];
  const float* W2    = (const float*)d_in[3];
  const float* b2    = (const float*)d_in[4];
  const float* fc1_w = (const float*)d_in[5];
  const float* fc1_b = (const float*)d_in[6];
  const float* fc2_w = (const float*)d_in[7];
  const float* fc2_b = (const float*)d_in[8];
  float* out = (float*)d_out;

  // workspace layout (bytes), ~30.7 MB total with aliasing:
  char* ws = (char*)d_ws;
  float* sqx  = (float*)(ws + 0);          //  64 KB
  float* sqh  = (float*)(ws + 65536);      //  64 KB
  int*   idx1 = (int*)  (ws + 131072);     //  1.25 MB
  int*   idx2 = (int*)  (ws + 1441792);    //  1.25 MB
  float* Wd2  = (float*)(ws + 2752512);    //  32 KB
  float* h1   = (float*)(ws + 2785280);    //  4 MB
  float* h2   = (float*)(ws + 6979584);    //  8 MB
  float* A    = (float*)(ws + 15368192);   //  8 MB: C1|G1 -> C2 -> f1
  float* C1   = A;
  float* G1   = (float*)(ws + 15368192 + 4194304);
  float* C2   = A;                          // C1/G1 dead after h1
  float* f1   = A;                          // C2 dead after h2
  float* G2   = (float*)(ws + 23756800);   //  8 MB  (end: 32,145,408)

  sq3_kernel   <<<64,   256, 0, stream>>>(x, sqx);
  knn3_kernel  <<<4096, 256, 0, stream>>>(x, sqx, idx1);
  cg1_kernel   <<<4096, 256, 0, stream>>>(x, W1, b1, C1, G1);
  maxrelu_kernel<64> <<<4096, 256, 0, stream>>>(C1, G1, idx1, h1);
  sq64_kernel  <<<64,   256, 0, stream>>>(h1, sqh);
  knn64_kernel <<<4096, 256, 0, stream>>>(h1, sqh, idx2);
  wd2_kernel   <<<32,   256, 0, stream>>>(W2, Wd2);
  cg2_kernel   <<<8192, 256, 0, stream>>>(h1, W2, Wd2, b2, C2, G2);
  maxrelu_kernel<128><<<8192, 256, 0, stream>>>(C2, G2, idx2, h2);
  fc1_kernel   <<<8192, 256, 0, stream>>>(h2, fc1_w, fc1_b, f1);
  fc2_kernel   <<<2560, 256, 0, stream>>>(f1, fc2_w, fc2_b, out);
}

// Round 3
// 7613.996 us; speedup vs baseline: 1.5727x; 1.5727x over previous
//
#include <hip/hip_runtime.h>
#include <math.h>

#define N_PTS 16384
#define KNN 20
#define NRANGE 8
#define C_RANGE (N_PTS / NRANGE)      // 2048
#define TILES_PER_RANGE (C_RANGE / 64) // 32

// ---------------- pack x + squared norm ----------------
__global__ void pack3_kernel(const float* __restrict__ x, float4* __restrict__ xp) {
  int i = blockIdx.x * blockDim.x + threadIdx.x;
  {
    #pragma clang fp contract(off)
    float a = x[i*3+0], b = x[i*3+1], c = x[i*3+2];
    xp[i] = make_float4(a, b, c, a*a + b*b + c*c);
  }
}

__global__ void sq64_kernel(const float* __restrict__ h, float* __restrict__ sq) {
  int i = blockIdx.x * blockDim.x + threadIdx.x;
  const float4* r = (const float4*)(h + (long)i*64);
  {
    #pragma clang fp contract(off)
    float ax=0.f, ay=0.f, az=0.f, aw=0.f;
    for (int t=0; t<16; t++) {
      float4 v = r[t];
      ax += v.x*v.x; ay += v.y*v.y; az += v.z*v.z; aw += v.w*v.w;
    }
    sq[i] = (ax+ay)+(az+aw);
  }
}

// ---------------- selection helper (device) ----------------
// thread-private sorted top-20 in LDS rows ld[q][0..19], li[q][0..19].
// Candidates processed in ascending index order; ties lose to earlier index
// (strict <), matching jax.lax.top_k stability.
__device__ __forceinline__ void select_from_dbuf(float* ldq, int* liq,
                                                 const float* dbq, int cbase) {
  float w19 = ldq[KNN-1];
  #pragma unroll
  for (int c4 = 0; c4 < 16; c4++) {
    float4 dv = *(const float4*)&dbq[c4*4];
    float mn = fminf(fminf(dv.x, dv.y), fminf(dv.z, dv.w));
    if (mn >= w19) continue;
    float ds[4] = {dv.x, dv.y, dv.z, dv.w};
    for (int k = 0; k < 4; k++) {
      float d = ds[k];
      if (d < w19) {
        int idx = cbase + c4*4 + k;
        int p = KNN-1;
        while (p > 0 && ldq[p-1] > d) { ldq[p] = ldq[p-1]; liq[p] = liq[p-1]; p--; }
        ldq[p] = d; liq[p] = idx;
        w19 = ldq[KNN-1];
      }
    }
  }
}

// ---------------- knn D=64, tiled ----------------
__global__ __launch_bounds__(256, 2) void knn64_tiled(const float* __restrict__ h,
                                                      const float* __restrict__ sq,
                                                      float* __restrict__ pd,
                                                      int* __restrict__ pi) {
  __shared__ float qbuf[64][68];   // [r][64] = sq(query)
  __shared__ float cbuf[64][68];   // [r][64] = sq(candidate)
  __shared__ float dbuf[64][72];
  __shared__ float ld[64][KNN];
  __shared__ int   li[64][KNN];
  int tid = threadIdx.x;
  int qb = blockIdx.x >> 3;
  int rg = blockIdx.x & 7;
  int q0 = qb*64, c0 = rg*C_RANGE;

  for (int t = tid; t < 64*16; t += 256) {
    int r = t >> 4, cc = t & 15;
    *(float4*)&qbuf[r][cc*4] = *(const float4*)(h + (size_t)(q0+r)*64 + cc*4);
  }
  if (tid < 64) qbuf[tid][64] = sq[q0+tid];
  for (int t = tid; t < 64*KNN; t += 256) { ld[t/KNN][t%KNN] = INFINITY; li[t/KNN][t%KNN] = 0x7fffffff; }

  int qrow0 = (tid >> 4) * 4;   // 16 groups of 4 query rows
  int tx = tid & 15;
  int crow0 = tx * 4;           // 16 groups of 4 candidate rows

  for (int tile = 0; tile < TILES_PER_RANGE; tile++) {
    int ct0 = c0 + tile*64;
    for (int t = tid; t < 64*16; t += 256) {
      int r = t >> 4, cc = t & 15;
      *(float4*)&cbuf[r][cc*4] = *(const float4*)(h + (size_t)(ct0+r)*64 + cc*4);
    }
    if (tid < 64) cbuf[tid][64] = sq[ct0+tid];
    __syncthreads();

    float acc[4][4];
    #pragma unroll
    for (int i=0;i<4;i++)
      #pragma unroll
      for (int j=0;j<4;j++) acc[i][j] = 0.f;

    #pragma unroll
    for (int dc = 0; dc < 16; dc++) {
      float4 qv[4], cv[4];
      #pragma unroll
      for (int i=0;i<4;i++) qv[i] = *(float4*)&qbuf[qrow0+i][dc*4];
      #pragma unroll
      for (int j=0;j<4;j++) cv[j] = *(float4*)&cbuf[crow0+j][dc*4];
      #pragma unroll
      for (int i=0;i<4;i++)
        #pragma unroll
        for (int j=0;j<4;j++)
          acc[i][j] += qv[i].x*cv[j].x + qv[i].y*cv[j].y + qv[i].z*cv[j].z + qv[i].w*cv[j].w;
    }

    float qs[4], cs[4];
    #pragma unroll
    for (int i=0;i<4;i++) qs[i] = qbuf[qrow0+i][64];
    #pragma unroll
    for (int j=0;j<4;j++) cs[j] = cbuf[crow0+j][64];
    #pragma unroll
    for (int i=0;i<4;i++) {
      float4 dv;
      dv.x = (qs[i] + cs[0]) - 2.0f*acc[i][0];
      dv.y = (qs[i] + cs[1]) - 2.0f*acc[i][1];
      dv.z = (qs[i] + cs[2]) - 2.0f*acc[i][2];
      dv.w = (qs[i] + cs[3]) - 2.0f*acc[i][3];
      *(float4*)&dbuf[qrow0+i][crow0] = dv;
    }
    __syncthreads();

    if (tid < 64) select_from_dbuf(ld[tid], li[tid], dbuf[tid], ct0);
    // next iteration's __syncthreads orders selection vs cbuf/dbuf rewrite
  }

  __syncthreads();
  for (int t = tid; t < 64*KNN; t += 256) {
    int q = t / KNN, k = t % KNN;
    size_t o = ((size_t)(q0+q)*NRANGE + rg)*KNN + k;
    pd[o] = ld[q][k];
    pi[o] = li[q][k];
  }
}

// ---------------- knn D=3 (packed float4), tiled ----------------
__global__ __launch_bounds__(256) void knn3_tiled(const float4* __restrict__ xp,
                                                  float* __restrict__ pd,
                                                  int* __restrict__ pi) {
  __shared__ float4 qb4[64];
  __shared__ float4 cb4[64];
  __shared__ float dbuf[64][72];
  __shared__ float ld[64][KNN];
  __shared__ int   li[64][KNN];
  int tid = threadIdx.x;
  int qb = blockIdx.x >> 3;
  int rg = blockIdx.x & 7;
  int q0 = qb*64, c0 = rg*C_RANGE;

  if (tid < 64) qb4[tid] = xp[q0+tid];
  for (int t = tid; t < 64*KNN; t += 256) { ld[t/KNN][t%KNN] = INFINITY; li[t/KNN][t%KNN] = 0x7fffffff; }

  int qrow0 = (tid >> 4) * 4;
  int tx = tid & 15;
  int crow0 = tx * 4;

  for (int tile = 0; tile < TILES_PER_RANGE; tile++) {
    int ct0 = c0 + tile*64;
    if (tid < 64) cb4[tid] = xp[ct0+tid];
    __syncthreads();

    float4 qv[4], cv[4];
    #pragma unroll
    for (int i=0;i<4;i++) qv[i] = qb4[qrow0+i];
    #pragma unroll
    for (int j=0;j<4;j++) cv[j] = cb4[crow0+j];
    #pragma unroll
    for (int i=0;i<4;i++) {
      float4 dv;
      float d0 = (qv[i].w + cv[0].w) - 2.0f*(qv[i].x*cv[0].x + qv[i].y*cv[0].y + qv[i].z*cv[0].z);
      float d1 = (qv[i].w + cv[1].w) - 2.0f*(qv[i].x*cv[1].x + qv[i].y*cv[1].y + qv[i].z*cv[1].z);
      float d2 = (qv[i].w + cv[2].w) - 2.0f*(qv[i].x*cv[2].x + qv[i].y*cv[2].y + qv[i].z*cv[2].z);
      float d3 = (qv[i].w + cv[3].w) - 2.0f*(qv[i].x*cv[3].x + qv[i].y*cv[3].y + qv[i].z*cv[3].z);
      dv.x=d0; dv.y=d1; dv.z=d2; dv.w=d3;
      *(float4*)&dbuf[qrow0+i][crow0] = dv;
    }
    __syncthreads();

    if (tid < 64) select_from_dbuf(ld[tid], li[tid], dbuf[tid], ct0);
  }

  __syncthreads();
  for (int t = tid; t < 64*KNN; t += 256) {
    int q = t / KNN, k = t % KNN;
    size_t o = ((size_t)(q0+q)*NRANGE + rg)*KNN + k;
    pd[o] = ld[q][k];
    pi[o] = li[q][k];
  }
}

// ---------------- merge 8 sorted partial lists -> top-20 ----------------
__global__ void knn_merge_kernel(const float* __restrict__ pd, const int* __restrict__ pi,
                                 int* __restrict__ out_idx) {
  int qi = blockIdx.x*256 + threadIdx.x;
  const float* bd = pd + (size_t)qi*NRANGE*KNN;
  const int*   bi = pi + (size_t)qi*NRANGE*KNN;
  int ptr[NRANGE];
  #pragma unroll
  for (int r=0;r<NRANGE;r++) ptr[r] = 0;
  for (int k = 0; k < KNN; k++) {
    float best = INFINITY; int besti = 0x7fffffff; int br = 0;
    #pragma unroll
    for (int r = 0; r < NRANGE; r++) {
      float d = bd[r*KNN + ptr[r]];   // ptr[r] < 20 always (each range has >=20 cands)
      int   ii = bi[r*KNN + ptr[r]];
      bool better = (ptr[r] < KNN) && (d < best || (d == best && ii < besti));
      if (better) { best = d; besti = ii; br = r; }
    }
    #pragma unroll
    for (int r=0;r<NRANGE;r++) ptr[r] += (r == br) ? 1 : 0;
    out_idx[qi*KNN + k] = besti;
  }
}

// ---------------- edge_conv1 precompute ----------------
__global__ void cg1_kernel(const float* __restrict__ x, const float* __restrict__ W1,
                           const float* __restrict__ b1,
                           float* __restrict__ C1, float* __restrict__ G1) {
  int gid = blockIdx.x*256 + threadIdx.x;   // 16384*64
  int i = gid >> 6, c = gid & 63;
  float x0 = x[i*3+0], x1 = x[i*3+1], x2 = x[i*3+2];
  float wt0 = W1[0*64+c], wt1 = W1[1*64+c], wt2 = W1[2*64+c];
  float wb0 = W1[3*64+c], wb1 = W1[4*64+c], wb2 = W1[5*64+c];
  C1[gid] = x0*(wt0-wb0) + x1*(wt1-wb1) + x2*(wt2-wb2) + b1[c];
  G1[gid] = x0*wb0 + x1*wb1 + x2*wb2;
}

// ---------------- gather + max + relu ----------------
template<int C>
__global__ void maxrelu_kernel(const float* __restrict__ Ci, const float* __restrict__ G,
                               const int* __restrict__ idx, float* __restrict__ out) {
  int gid = blockIdx.x*256 + threadIdx.x;
  int i = gid / C, c = gid % C;
  float base = Ci[gid];
  float m = -INFINITY;
  for (int j=0; j<KNN; j++) {
    int jj = idx[i*KNN + j];
    m = fmaxf(m, base + G[(long)jj*C + c]);
  }
  out[gid] = fmaxf(m, 0.0f);
}

// ---------------- W2 diff ----------------
__global__ void wd2_kernel(const float* __restrict__ W2, float* __restrict__ Wd) {
  int gid = blockIdx.x*256 + threadIdx.x;   // 64*128
  int d = gid >> 7, c = gid & 127;
  Wd[gid] = W2[d*128+c] - W2[(d+64)*128+c];
}

// ---------------- edge_conv2 precompute ----------------
__global__ void cg2_kernel(const float* __restrict__ h1, const float* __restrict__ W2,
                           const float* __restrict__ Wd, const float* __restrict__ b2,
                           float* __restrict__ C2, float* __restrict__ G2) {
  int gid = blockIdx.x*256 + threadIdx.x;   // 16384*128
  int i = gid >> 7, c = gid & 127;
  float a = 0.f, g = 0.f;
  for (int d=0; d<64; d++) {
    float hv = h1[i*64 + d];
    a += hv * Wd[d*128 + c];
    g += hv * W2[(d+64)*128 + c];
  }
  C2[gid] = a + b2[c];
  G2[gid] = g;
}

// ---------------- fc1 (relu) ----------------
__global__ void fc1_kernel(const float* __restrict__ h2, const float* __restrict__ w,
                           const float* __restrict__ b, float* __restrict__ out) {
  int gid = blockIdx.x*256 + threadIdx.x;   // 16384*128
  int i = gid >> 7, c = gid & 127;
  float a = 0.f;
  for (int d=0; d<128; d++) a += h2[i*128+d] * w[d*128+c];
  out[gid] = fmaxf(a + b[c], 0.0f);
}

// ---------------- fc2 ----------------
__global__ void fc2_kernel(const float* __restrict__ f1, const float* __restrict__ w,
                           const float* __restrict__ b, float* __restrict__ out) {
  int gid = blockIdx.x*256 + threadIdx.x;   // 16384*40
  int i = gid / 40, c = gid - i*40;
  float a = 0.f;
  for (int d=0; d<128; d++) a += f1[i*128+d] * w[d*40+c];
  out[gid] = a + b[c];
}

extern "C" void kernel_launch(void* const* d_in, const int* in_sizes, int n_in,
                              void* d_out, int out_size, void* d_ws, size_t ws_size,
                              hipStream_t stream) {
  (void)in_sizes; (void)n_in; (void)out_size; (void)ws_size;
  const float* x     = (const float*)d_in[0];
  const float* W1    = (const float*)d_in[1];
  const float* b1    = (const float*)d_in[2];
  const float* W2    = (const float*)d_in[3];
  const float* b2    = (const float*)d_in[4];
  const float* fc1_w = (const float*)d_in[5];
  const float* fc1_b = (const float*)d_in[6];
  const float* fc2_w = (const float*)d_in[7];
  const float* fc2_b = (const float*)d_in[8];
  float* out = (float*)d_out;

  // ---- workspace layout (31.03 MB total, aliased) ----
  // pd/pi (partial knn lists, 10.49 MB each) alias h2+A+G2, which are dead
  // during both knn phases; C/G/f regions only go live after the merges.
  char* ws = (char*)d_ws;
  float4* xp4 = (float4*)(ws + 0);          // 262144
  float*  sqh = (float*) (ws + 262144);     // 65536
  int*    idx = (int*)   (ws + 327680);     // 1310720 (idx1 then idx2)
  float*  Wd2 = (float*) (ws + 1638400);    // 32768
  float*  h1  = (float*) (ws + 1671168);    // 4194304  -> ends 5865472
  float*  h2  = (float*) (ws + 5865472);    // 8388608  -> ends 14254080
  float*  A   = (float*) (ws + 14254080);   // 8388608  -> ends 22642688
  float*  C1  = A;
  float*  G1  = (float*) (ws + 14254080 + 4194304);
  float*  C2  = A;
  float*  f1  = A;
  float*  G2  = (float*) (ws + 22642688);   // 8388608  -> ends 31031296
  float*  pd  = (float*) (ws + 5865472);    // 10485760 -> ends 16351232
  int*    pi  = (int*)   (ws + 16351232);   // 10485760 -> ends 26836992

  pack3_kernel <<<64,   256, 0, stream>>>(x, xp4);
  knn3_tiled   <<<2048, 256, 0, stream>>>(xp4, pd, pi);
  knn_merge_kernel<<<64,256, 0, stream>>>(pd, pi, idx);
  cg1_kernel   <<<4096, 256, 0, stream>>>(x, W1, b1, C1, G1);
  maxrelu_kernel<64> <<<4096, 256, 0, stream>>>(C1, G1, idx, h1);
  sq64_kernel  <<<64,   256, 0, stream>>>(h1, sqh);
  knn64_tiled  <<<2048, 256, 0, stream>>>(h1, sqh, pd, pi);
  knn_merge_kernel<<<64,256, 0, stream>>>(pd, pi, idx);
  wd2_kernel   <<<32,   256, 0, stream>>>(W2, Wd2);
  cg2_kernel   <<<8192, 256, 0, stream>>>(h1, W2, Wd2, b2, C2, G2);
  maxrelu_kernel<128><<<8192, 256, 0, stream>>>(C2, G2, idx, h2);
  fc1_kernel   <<<8192, 256, 0, stream>>>(h2, fc1_w, fc1_b, f1);
  fc2_kernel   <<<2560, 256, 0, stream>>>(f1, fc2_w, fc2_b, out);
}